// Round 6
// baseline (132.481 us; speedup 1.0000x reference)
//
#include <hip/hip_runtime.h>

#define GAMMA 0.1f
#define EPS_F 1e-12f

// ---- binned-path configuration ----
#define NBKT 40          // dst buckets (windows of W_NODES)
#define W_NODES 2500     // nodes per bucket window (dl fits 15 bits)
#define NBIN 256         // scatter blocks == runs per bucket
#define CAP 640          // per-(bucket,block) region capacity (mean ~313, 16 sigma)
#define TILE 4096        // edges staged per scatter tile (1024 thr x 4)
#define BIN_THREADS 1024
#define SCAN_THREADS 1024
#define B_DENSE 16       // dense blocks per bucket; 16 waves -> 1 run/wave

// ---- legacy-path configuration ----
#define S_NODES 20000
#define B_TARGET 51

// ================= binned pipeline (3 dispatches) =================

// scatter_perm: tile-staged scatter. Per 4096-edge tile: LDS histogram with
// rank (atomicAdd return) -> wave0 prefix -> permute (val,dst) into LDS in
// bucket-major order -> cooperative copy (consecutive lanes -> consecutive
// global addrs within ~100-edge segments). Kills the 64B-line-per-4B-store
// write amplification measured in round 4 (~200 MB -> ~13 MB).
__global__ __launch_bounds__(BIN_THREADS)
void scatter_perm_kernel(const int* __restrict__ src,
                         const int* __restrict__ dst,
                         unsigned* __restrict__ ebuf,
                         int* __restrict__ cnt,
                         int e, int bchunk) {
    __shared__ int cur[NBKT];        // region-relative running cursor
    __shared__ int tcnt[NBKT];       // per-tile histogram
    __shared__ int tbase[NBKT];      // per-tile exclusive prefix (stage base)
    __shared__ int dbase[NBKT];      // per-tile dest-base snapshot of cur
    __shared__ unsigned sval[TILE];
    __shared__ int sdst[TILE];       // absolute ebuf index (-1 = drop)
    int tid = threadIdx.x;
    int b = blockIdx.x;
    if (tid < NBKT) cur[tid] = 0;
    int start = b * bchunk;
    int end = min(start + bchunk, e);

    for (int t0 = start; t0 < end; t0 += TILE) {
        int tlen = min(TILE, end - t0);
        if (tid < NBKT) tcnt[tid] = 0;
        __syncthreads();                       // reset visible; prev copy done

        // load 4 edges (coalesced int4 when fully in range)
        int ei = t0 + (tid << 2);
        int dv[4], sv[4];
        bool val[4];
        if (ei + 3 < end) {
            int4 d4 = *(const int4*)(dst + ei);
            int4 s4 = *(const int4*)(src + ei);
            dv[0] = d4.x; dv[1] = d4.y; dv[2] = d4.z; dv[3] = d4.w;
            sv[0] = s4.x; sv[1] = s4.y; sv[2] = s4.z; sv[3] = s4.w;
            val[0] = val[1] = val[2] = val[3] = true;
        } else {
            #pragma unroll
            for (int u = 0; u < 4; ++u) {
                val[u] = (ei + u) < end;
                dv[u] = val[u] ? dst[ei + u] : 0;
                sv[u] = val[u] ? src[ei + u] : 0;
            }
        }
        int kk[4], rr[4];
        unsigned vv[4];
        #pragma unroll
        for (int u = 0; u < 4; ++u) {
            if (val[u]) {
                int k = dv[u] / W_NODES;
                kk[u] = k;
                vv[u] = ((unsigned)(dv[u] - k * W_NODES) << 17) | (unsigned)sv[u];
                rr[u] = atomicAdd(&tcnt[k], 1);
            }
        }
        __syncthreads();                       // histogram complete

        if (tid < 64) {                        // wave0: exclusive prefix + cursors
            int c = (tid < NBKT) ? tcnt[tid] : 0;
            int incl = c;
            #pragma unroll
            for (int d = 1; d < 64; d <<= 1) {
                int t = __shfl_up(incl, d);
                if (tid >= d) incl += t;
            }
            if (tid < NBKT) {
                tbase[tid] = incl - c;
                int cu = cur[tid];
                dbase[tid] = cu;
                cur[tid] = cu + c;
            }
        }
        __syncthreads();                       // tbase/dbase visible

        #pragma unroll
        for (int u = 0; u < 4; ++u) {
            if (val[u]) {
                int pos = tbase[kk[u]] + rr[u];
                sval[pos] = vv[u];
                int drel = dbase[kk[u]] + rr[u];
                sdst[pos] = (drel < CAP)
                              ? (kk[u] * NBIN + b) * CAP + drel
                              : -1;            // statistically unreachable
            }
        }
        __syncthreads();                       // staging visible

        for (int i = tid; i < tlen; i += BIN_THREADS) {
            int dd = sdst[i];
            if (dd >= 0) ebuf[dd] = sval[i];
        }
        // next iteration's first barrier guarantees copy completion
    }
    __syncthreads();
    if (tid < NBKT) cnt[tid * NBIN + b] = min(cur[tid], CAP);
}

// dense: block (p,b) = bucket p, runs [b*16, b*16+16), one run per wave.
// LDS window accumulate (SoA), plain coalesced float4 partial stores
// (NO global atomics -- round 4 measured those at 19.2 MB HBM RMW / 47us).
#define PROC(w, xs) do {                                          \
    int dl_ = (int)((w) >> 17);                                   \
    float2 xd_ = xwin[dl_];                                       \
    float dx_ = xd_.x - (xs).x;                                   \
    float dy_ = xd_.y - (xs).y;                                   \
    float d2_ = dx_ * dx_ + dy_ * dy_;                            \
    float ir_ = d2_ > 0.f ? __builtin_amdgcn_rsqf(d2_) : 0.f;     \
    float sc_ = 2.f * ir_ - 2.f;                                  \
    atomicAdd(&accx[dl_], sc_ * dx_);                             \
    atomicAdd(&accy[dl_], sc_ * dy_);                             \
} while (0)

__global__ __launch_bounds__(SCAN_THREADS, 8)   // 2 blocks/CU (thread-capped)
void dense_kernel(const float2* __restrict__ x,
                  const unsigned* __restrict__ ebuf,
                  const int* __restrict__ cnt,
                  float2* __restrict__ wsp, int n) {
    __shared__ float accx[W_NODES];
    __shared__ float accy[W_NODES];
    __shared__ float2 xwin[W_NODES];
    int p = blockIdx.x / B_DENSE;
    int b = blockIdx.x - p * B_DENSE;
    int lo = p * W_NODES;
    int tid = threadIdx.x;
    for (int i = tid; i < W_NODES; i += SCAN_THREADS) {
        accx[i] = 0.f;
        accy[i] = 0.f;
    }
    int nw = min(W_NODES, n - lo);               // <=0 for empty tail buckets
    for (int i = tid; i < nw; i += SCAN_THREADS) xwin[i] = x[lo + i];
    __syncthreads();

    int wid = tid >> 6;
    int lane = tid & 63;
    int r = b * (NBIN / B_DENSE) + wid;          // one run per wave, balanced
    int len = cnt[p * NBIN + r];
    const unsigned* run = ebuf + (size_t)(p * NBIN + r) * CAP;
    int i = lane;
    for (; i + 192 < len; i += 256) {            // 4-deep independent gathers
        unsigned w0 = run[i];
        unsigned w1 = run[i + 64];
        unsigned w2 = run[i + 128];
        unsigned w3 = run[i + 192];
        float2 xs0 = x[w0 & 0x1FFFFu];
        float2 xs1 = x[w1 & 0x1FFFFu];
        float2 xs2 = x[w2 & 0x1FFFFu];
        float2 xs3 = x[w3 & 0x1FFFFu];
        PROC(w0, xs0);
        PROC(w1, xs1);
        PROC(w2, xs2);
        PROC(w3, xs3);
    }
    for (; i < len; i += 64) {
        unsigned w = run[i];
        float2 xs = x[w & 0x1FFFFu];
        PROC(w, xs);
    }
    __syncthreads();
    // coalesced 16B partial stores (W_NODES*8 = 20000B per block, 16B aligned)
    float4* w4 = (float4*)(wsp + (size_t)blockIdx.x * W_NODES);
    for (int j = tid; j < W_NODES / 2; j += SCAN_THREADS)
        w4[j] = make_float4(accx[2 * j], accy[2 * j],
                            accx[2 * j + 1], accy[2 * j + 1]);
}

__global__ __launch_bounds__(256)
void reduce_bin_kernel(const float2* __restrict__ ws,
                       const float2* __restrict__ v,
                       float2* __restrict__ out, int n) {
    int i = blockIdx.x * blockDim.x + threadIdx.x;
    if (i >= n) return;
    int p = i / W_NODES;
    int loc = i - p * W_NODES;
    const float2* base = ws + (size_t)(p * B_DENSE) * W_NODES + loc;
    float sx0 = 0.f, sy0 = 0.f, sx1 = 0.f, sy1 = 0.f;
    float sx2 = 0.f, sy2 = 0.f, sx3 = 0.f, sy3 = 0.f;
    #pragma unroll
    for (int b = 0; b < B_DENSE; b += 4) {       // 4 independent loads in flight
        float2 t0 = base[(size_t)(b + 0) * W_NODES];
        float2 t1 = base[(size_t)(b + 1) * W_NODES];
        float2 t2 = base[(size_t)(b + 2) * W_NODES];
        float2 t3 = base[(size_t)(b + 3) * W_NODES];
        sx0 += t0.x; sy0 += t0.y; sx1 += t1.x; sy1 += t1.y;
        sx2 += t2.x; sy2 += t2.y; sx3 += t3.x; sy3 += t3.y;
    }
    float2 vi = v[i];
    out[i] = make_float2((sx0 + sx1) + (sx2 + sx3) - GAMMA * vi.x,
                         (sy0 + sy1) + (sy2 + sy3) - GAMMA * vi.y);
}

// ================= legacy path (fallback) =================

#define EDGE(dd, ss) do {                                        \
    int d_ = (dd);                                               \
    if (d_ >= lo && d_ < hi) {                                   \
        float2 xs = x[(ss)];                                     \
        float2 xd = x[d_];                                       \
        float dx = xd.x - xs.x;                                  \
        float dy = xd.y - xs.y;                                  \
        float r = sqrtf(dx * dx + dy * dy);                      \
        float sc = -2.0f * (r - 1.0f) / fmaxf(r, EPS_F);         \
        atomicAdd(&acc[d_ - lo].x, sc * dx);                     \
        atomicAdd(&acc[d_ - lo].y, sc * dy);                     \
    }                                                            \
} while (0)

__global__ __launch_bounds__(SCAN_THREADS, 1)
void scan_kernel(const float2* __restrict__ x,
                 const int4* __restrict__ src4,
                 const int4* __restrict__ dst4,
                 const int* __restrict__ src,
                 const int* __restrict__ dst,
                 float2* __restrict__ ws,
                 int e, int n, int B, int chunk) {
    __shared__ float2 acc[S_NODES];
    int p = blockIdx.x / B;
    int b = blockIdx.x - p * B;
    int lo = p * S_NODES;
    int hi = min(lo + S_NODES, n);
    int tid = threadIdx.x;

    for (int i = tid; i < S_NODES; i += SCAN_THREADS)
        acc[i] = make_float2(0.f, 0.f);
    __syncthreads();

    int estart = b * chunk;
    int eend = min(estart + chunk, e);
    if (estart < eend) {
        int nvec = (eend - estart) >> 2;
        const int4* d4p = dst4 + (estart >> 2);
        const int4* s4p = src4 + (estart >> 2);
        int nvec2 = nvec >> 1;
        for (int i = tid; i < nvec2; i += SCAN_THREADS) {
            int4 da = d4p[i];
            int4 sa = s4p[i];
            int4 db = d4p[i + nvec2];
            int4 sb = s4p[i + nvec2];
            EDGE(da.x, sa.x);
            EDGE(da.y, sa.y);
            EDGE(da.z, sa.z);
            EDGE(da.w, sa.w);
            EDGE(db.x, sb.x);
            EDGE(db.y, sb.y);
            EDGE(db.z, sb.z);
            EDGE(db.w, sb.w);
        }
        for (int i = (nvec2 << 1) + tid; i < nvec; i += SCAN_THREADS) {
            int4 d4 = d4p[i];
            int4 s4 = s4p[i];
            EDGE(d4.x, s4.x);
            EDGE(d4.y, s4.y);
            EDGE(d4.z, s4.z);
            EDGE(d4.w, s4.w);
        }
        for (int i = estart + (nvec << 2) + tid; i < eend; i += SCAN_THREADS)
            EDGE(dst[i], src[i]);
    }
    __syncthreads();

    float2* wsb = ws + (size_t)blockIdx.x * S_NODES;
    for (int i = tid; i < S_NODES; i += SCAN_THREADS)
        wsb[i] = acc[i];
}

__global__ __launch_bounds__(256)
void reduce_kernel(const float2* __restrict__ ws,
                   const float2* __restrict__ v,
                   float2* __restrict__ out,
                   int n, int B) {
    int i = blockIdx.x * blockDim.x + threadIdx.x;
    if (i >= n) return;
    int p = i / S_NODES;
    int loc = i - p * S_NODES;
    const float2* base = ws + ((size_t)(p * B) * S_NODES + loc);
    float sx0 = 0.f, sy0 = 0.f, sx1 = 0.f, sy1 = 0.f;
    float sx2 = 0.f, sy2 = 0.f, sx3 = 0.f, sy3 = 0.f;
    int b = 0;
    for (; b + 8 <= B; b += 8) {
        float2 t0 = base[(size_t)(b + 0) * S_NODES];
        float2 t1 = base[(size_t)(b + 1) * S_NODES];
        float2 t2 = base[(size_t)(b + 2) * S_NODES];
        float2 t3 = base[(size_t)(b + 3) * S_NODES];
        float2 t4 = base[(size_t)(b + 4) * S_NODES];
        float2 t5 = base[(size_t)(b + 5) * S_NODES];
        float2 t6 = base[(size_t)(b + 6) * S_NODES];
        float2 t7 = base[(size_t)(b + 7) * S_NODES];
        sx0 += t0.x; sy0 += t0.y; sx1 += t1.x; sy1 += t1.y;
        sx2 += t2.x; sy2 += t2.y; sx3 += t3.x; sy3 += t3.y;
        sx0 += t4.x; sy0 += t4.y; sx1 += t5.x; sy1 += t5.y;
        sx2 += t6.x; sy2 += t6.y; sx3 += t7.x; sy3 += t7.y;
    }
    for (; b < B; ++b) {
        float2 t = base[(size_t)b * S_NODES];
        sx0 += t.x; sy0 += t.y;
    }
    float sx = (sx0 + sx1) + (sx2 + sx3);
    float sy = (sy0 + sy1) + (sy2 + sy3);
    float2 vi = v[i];
    out[i] = make_float2(sx - GAMMA * vi.x, sy - GAMMA * vi.y);
}

__global__ void init_out_kernel(const float2* __restrict__ v,
                                float2* __restrict__ out, int n) {
    int i = blockIdx.x * blockDim.x + threadIdx.x;
    if (i < n) {
        float2 vi = v[i];
        out[i] = make_float2(-GAMMA * vi.x, -GAMMA * vi.y);
    }
}

__device__ __forceinline__ void do_edge_atomic(const float2* __restrict__ x,
                                               int s, int d,
                                               float* __restrict__ out) {
    float2 xs = x[s];
    float2 xd = x[d];
    float dx = xd.x - xs.x;
    float dy = xd.y - xs.y;
    float r = sqrtf(dx * dx + dy * dy);
    float sc = -2.0f * (r - 1.0f) / fmaxf(r, EPS_F);
    atomicAdd(&out[2 * d], sc * dx);
    atomicAdd(&out[2 * d + 1], sc * dy);
}

__global__ void edge_kernel_atomic(const float2* __restrict__ x,
                                   const int4* __restrict__ src4,
                                   const int4* __restrict__ dst4,
                                   const int* __restrict__ src,
                                   const int* __restrict__ dst,
                                   float* __restrict__ out,
                                   int e4, int e_total) {
    int i = blockIdx.x * blockDim.x + threadIdx.x;
    if (i < e4) {
        int4 s = src4[i];
        int4 d = dst4[i];
        do_edge_atomic(x, s.x, d.x, out);
        do_edge_atomic(x, s.y, d.y, out);
        do_edge_atomic(x, s.z, d.z, out);
        do_edge_atomic(x, s.w, d.w, out);
    }
    if (i == 0) {
        for (int e = e4 * 4; e < e_total; ++e)
            do_edge_atomic(x, src[e], dst[e], out);
    }
}

extern "C" void kernel_launch(void* const* d_in, const int* in_sizes, int n_in,
                              void* d_out, int out_size, void* d_ws, size_t ws_size,
                              hipStream_t stream) {
    const float2* x = (const float2*)d_in[0];   // [N,2] fp32
    const float2* v = (const float2*)d_in[1];   // [N,2] fp32
    const int* src  = (const int*)d_in[2];      // [E] int32
    const int* dst  = (const int*)d_in[3];      // [E] int32

    int n = in_sizes[0] / 2;   // N nodes
    int e = in_sizes[2];       // E edges

    float* out = (float*)d_out;

    // ---- binned path workspace: [ebuf][cnt][partials] ----
    size_t ebuf_bytes = (size_t)NBKT * NBIN * CAP * 4;           // 26.2 MB
    size_t cnt_off    = (ebuf_bytes + 1023) & ~(size_t)1023;
    size_t part_off   = (cnt_off + (size_t)NBKT * NBIN * 4 + 1023) & ~(size_t)1023;
    size_t need       = part_off +
                        (size_t)NBKT * B_DENSE * W_NODES * sizeof(float2);

    // gates: window coverage, 17-bit src pack, CAP >=9 sigma margin
    if (n >= 1 && n <= NBKT * W_NODES && n < (1 << 17) &&
        e >= 1 && e <= 4500000 && ws_size >= need) {
        char* wsc = (char*)d_ws;
        unsigned* ebuf = (unsigned*)wsc;
        int* cnt = (int*)(wsc + cnt_off);
        float2* wsp = (float2*)(wsc + part_off);
        int bchunk = (((e + NBIN - 1) / NBIN) + 3) & ~3;   // 4-aligned
        scatter_perm_kernel<<<NBIN, BIN_THREADS, 0, stream>>>(
            src, dst, ebuf, cnt, e, bchunk);
        dense_kernel<<<NBKT * B_DENSE, SCAN_THREADS, 0, stream>>>(
            x, ebuf, cnt, wsp, n);
        int threads = 256;
        reduce_bin_kernel<<<(n + threads - 1) / threads, threads, 0, stream>>>(
            wsp, v, (float2*)out, n);
        return;
    }

    // ---- legacy paths ----
    int P = (n + S_NODES - 1) / S_NODES;
    size_t per_b = (size_t)P * S_NODES * sizeof(float2);
    int Bmax = (per_b > 0) ? (int)(ws_size / per_b) : 0;
    int Bl = B_TARGET < Bmax ? B_TARGET : Bmax;

    if (Bl >= 1) {
        int chunk = (((e + Bl - 1) / Bl) + 3) & ~3;
        scan_kernel<<<P * Bl, SCAN_THREADS, 0, stream>>>(
            x, (const int4*)src, (const int4*)dst, src, dst,
            (float2*)d_ws, e, n, Bl, chunk);
        int threads = 256;
        reduce_kernel<<<(n + threads - 1) / threads, threads, 0, stream>>>(
            (const float2*)d_ws, v, (float2*)out, n, Bl);
    } else {
        int threads = 256;
        init_out_kernel<<<(n + threads - 1) / threads, threads, 0, stream>>>(
            v, (float2*)out, n);
        int e4 = e / 4;
        int blocks = (e4 + threads - 1) / threads;
        if (blocks < 1) blocks = 1;
        edge_kernel_atomic<<<blocks, threads, 0, stream>>>(
            x, (const int4*)src, (const int4*)dst, src, dst, out, e4, e);
    }
}